// Round 9
// baseline (1426.415 us; speedup 1.0000x reference)
//
#include <hip/hip_runtime.h>
#include <hip/hip_bf16.h>
#include <hip/hip_cooperative_groups.h>

namespace cg = cooperative_groups;

// GCN encoder: 3 layers on N=100000 nodes, E=1250000 edges, 64 features.
// gcn(x) = relu(D^-1/2 (A+I) D^-1/2 (xW) + b)
// hs = dinv.*(xW) [gemm->bf16]; aggregate epilogue emits
// bf16(relu(dinv*(hs_d + sum hs_s) + b)) = next gemm's input.
// R8 post-mortem: coop launch of 512 blocks (needs 2 blocks/CU) was rejected
//   -> zero output, never ran. R9: 256 blocks x 1024 thr (1 block/CU always
//   satisfiable: LDS 85.6KB, launch_bounds(1024,4) caps VGPR 128) + checked
//   return code with full R7 multi-kernel fallback.

#define NBLK 256
#define NTHR 1024
#define WG 256                   // fallback kernels' block size
#define BSHIFT 9                 // 512 nodes per bucket
#define BSIZE  (1 << BSHIFT)
#define BCAP   8192              // slots per bucket (mean 6400, ~22 sigma margin)
#define PCHUNK 2048              // edges per partition chunk
#define XS_LD  68                // xs leading dim: 16B-aligned, b128 reads

// ============================ mega (cooperative) ============================

struct SmemP {                   // partition phase
    int hist[256], gbase[256], lb[256], wtot[16], wpre[16];
    unsigned long long sp[PCHUNK];
    int sd[PCHUNK];
};
struct SmemC {                   // csr_local phase
    int h[BSIZE], cur[BSIZE], bbs[256], wtot[16], wpre[16];
};
struct SmemG {                   // gemm phase (256-row tile)
    float Ws[64 * 64];
    float xs[256 * XS_LD];
};
union Smem { SmemP p; SmemC c; SmemG g; };

__device__ __forceinline__ void gemm_phase(
    Smem& sm, const void* in, int in_bf16, const float* W,
    const float* dinv, int post_scale, const float* b_post,
    void* out1, int out_bf16, int n_rows)
{
    const int t = threadIdx.x;
    __syncthreads();                       // LDS region handoff
    ((float4*)sm.g.Ws)[t] = ((const float4*)W)[t];   // 4096 floats = 1024 f4

    const int ntiles = (n_rows + 255) / 256;
    const int fg = (t & 15) * 4;
    const int r0 = (t >> 4) * 4;           // 0..252

    for (int tile = blockIdx.x; tile < ntiles; tile += gridDim.x) {
        const int row0 = tile * 256;
        __syncthreads();                   // xs reuse guard
#pragma unroll
        for (int i = 0; i < 4; i++) {      // 4096 float4 slots
            int j = i * NTHR + t;
            int rr = j >> 4;               // 0..255
            int c  = (j & 15) * 4;
            int row = row0 + rr;
            float4 v = make_float4(0.f, 0.f, 0.f, 0.f);
            if (row < n_rows) {
                if (in_bf16) {
                    ushort4 u = *(const ushort4*)((const unsigned short*)in +
                                                  ((size_t)row << 6) + c);
                    union { unsigned q; float f; } a0, a1, a2, a3;
                    a0.q = (unsigned)u.x << 16; a1.q = (unsigned)u.y << 16;
                    a2.q = (unsigned)u.z << 16; a3.q = (unsigned)u.w << 16;
                    v = make_float4(a0.f, a1.f, a2.f, a3.f);
                } else {
                    v = *(const float4*)((const float*)in + ((size_t)row << 6) + c);
                }
            }
            float* xp = sm.g.xs + rr * XS_LD + c;
            xp[0] = v.x; xp[1] = v.y; xp[2] = v.z; xp[3] = v.w;
        }
        __syncthreads();

        float acc[4][4] = {};
#pragma unroll
        for (int kq = 0; kq < 64; kq += 4) {
            float4 xr[4];
#pragma unroll
            for (int r = 0; r < 4; r++)
                xr[r] = *(const float4*)(sm.g.xs + (r0 + r) * XS_LD + kq);
#pragma unroll
            for (int kk = 0; kk < 4; kk++) {
                float4 wv = *(const float4*)(sm.g.Ws + (kq + kk) * 64 + fg);
#pragma unroll
                for (int r = 0; r < 4; r++) {
                    float xv = ((const float*)&xr[r])[kk];
                    acc[r][0] = fmaf(xv, wv.x, acc[r][0]);
                    acc[r][1] = fmaf(xv, wv.y, acc[r][1]);
                    acc[r][2] = fmaf(xv, wv.z, acc[r][2]);
                    acc[r][3] = fmaf(xv, wv.w, acc[r][3]);
                }
            }
        }

        float4 bp = b_post ? *(const float4*)(b_post + fg)
                           : make_float4(0.f, 0.f, 0.f, 0.f);
#pragma unroll
        for (int r = 0; r < 4; r++) {
            int row = row0 + r0 + r;
            if (row >= n_rows) break;
            float sc = post_scale ? dinv[row] : 1.0f;
            float4 o;
            o.x = fmaf(acc[r][0], sc, bp.x);
            o.y = fmaf(acc[r][1], sc, bp.y);
            o.z = fmaf(acc[r][2], sc, bp.z);
            o.w = fmaf(acc[r][3], sc, bp.w);
            if (out_bf16) {
                union { __hip_bfloat16 h[4]; ushort4 u; } pk;
                pk.h[0] = __float2bfloat16(o.x);
                pk.h[1] = __float2bfloat16(o.y);
                pk.h[2] = __float2bfloat16(o.z);
                pk.h[3] = __float2bfloat16(o.w);
                *(ushort4*)((unsigned short*)out1 + ((size_t)row << 6) + fg) = pk.u;
            } else {
                *(float4*)((float*)out1 + ((size_t)row << 6) + fg) = o;
            }
        }
    }
}

__device__ __forceinline__ void agg_phase(
    const __hip_bfloat16* A, __hip_bfloat16* O,
    const int* off, const int* csr,
    const float* dinv, const float* bias, int N)
{
    const int lane = threadIdx.x & 63;
    const int wid = threadIdx.x >> 6;      // 0..15
    const int ngrp = (N + 15) / 16;
    for (int grp = blockIdx.x; grp < ngrp; grp += gridDim.x) {
        int node = grp * 16 + wid;
        if (node >= N) continue;
        int s0 = off[node];
        int s1 = off[node + 1];
        float acc = __bfloat162float(A[((size_t)node << 6) + lane]);  // self-loop
        int e = s0;
        for (; e + 4 <= s1; e += 4) {
            int i0 = csr[e], i1 = csr[e + 1], i2 = csr[e + 2], i3 = csr[e + 3];
            float v0 = __bfloat162float(A[((size_t)i0 << 6) + lane]);
            float v1 = __bfloat162float(A[((size_t)i1 << 6) + lane]);
            float v2 = __bfloat162float(A[((size_t)i2 << 6) + lane]);
            float v3 = __bfloat162float(A[((size_t)i3 << 6) + lane]);
            acc += (v0 + v1) + (v2 + v3);
        }
        for (; e < s1; e++)
            acc += __bfloat162float(A[((size_t)csr[e] << 6) + lane]);
        float v = fmaxf(fmaf(dinv[node], acc, bias[lane]), 0.f);
        O[((size_t)node << 6) + lane] = __float2bfloat16(v);
    }
}

__global__ __launch_bounds__(NTHR, 4) void mega(
    const float* __restrict__ x, const int* __restrict__ ei,
    const float* __restrict__ W1, const float* __restrict__ b1,
    const float* __restrict__ W2, const float* __restrict__ b2,
    const float* __restrict__ W3, const float* __restrict__ b3,
    float* __restrict__ out,
    int* __restrict__ off, int* __restrict__ csr, int* __restrict__ cur2,
    float* __restrict__ dinv, unsigned long long* __restrict__ pairs,
    __hip_bfloat16* __restrict__ Abuf, __hip_bfloat16* __restrict__ H,
    int N, int E, int nbk)
{
    __shared__ Smem sm;
    cg::grid_group grid = cg::this_grid();
    const int t = threadIdx.x;
    const int lane = t & 63, w = t >> 6;

    // ---- P0: zero bucket counters ----
    if (blockIdx.x == 0) {
        if (t < 256) cur2[t] = 0;
        if (t == 0) off[N] = E;
    }
    grid.sync();

    // ---- P1: partition edges into per-bucket slabs ----
    {
        const int nch = (E + PCHUNK - 1) / PCHUNK;
        for (int ch = blockIdx.x; ch < nch; ch += gridDim.x) {
            const int base = ch * PCHUNK;
            const int total = min(PCHUNK, E - base);
            __syncthreads();               // LDS reuse guard
            if (t < 256) sm.p.hist[t] = 0;
            __syncthreads();

            int s[2], d[2], r[2];
#pragma unroll
            for (int i = 0; i < 2; i++) {
                int e = base + i * NTHR + t;
                bool ok = e < E;
                s[i] = ok ? ei[e] : 0;
                d[i] = ok ? ei[E + e] : 0;
                r[i] = ok ? atomicAdd(&sm.p.hist[d[i] >> BSHIFT], 1) : 0;
                if (!ok) d[i] = -1;
            }
            __syncthreads();

            if (t < 256) {                 // waves 0..3
                int hv = sm.p.hist[t];
                int old = (hv > 0) ? atomicAdd(&cur2[t], hv) : 0;
                sm.p.gbase[t] = t * BCAP + old;
                int incl = hv;
#pragma unroll
                for (int ofs = 1; ofs < 64; ofs <<= 1) {
                    int u = __shfl_up(incl, ofs);
                    if (lane >= ofs) incl += u;
                }
                if (lane == 63) sm.p.wtot[w] = incl;
                sm.p.lb[t] = incl - hv;
            }
            __syncthreads();
            if (t == 0) {
                int run = 0;
#pragma unroll
                for (int j = 0; j < 4; j++) { sm.p.wpre[j] = run; run += sm.p.wtot[j]; }
            }
            __syncthreads();

#pragma unroll
            for (int i = 0; i < 2; i++) {
                if (d[i] >= 0) {
                    int b = d[i] >> BSHIFT;
                    int slot = sm.p.wpre[b >> 6] + sm.p.lb[b] + r[i];
                    sm.p.sp[slot] = ((unsigned long long)(unsigned)(d[i] & (BSIZE - 1)) << 32) |
                                    (unsigned)s[i];
                    sm.p.sd[slot] = sm.p.gbase[b] + r[i];
                }
            }
            __syncthreads();
            for (int j = t; j < total; j += NTHR)
                pairs[sm.p.sd[j]] = sm.p.sp[j];
        }
    }
    grid.sync();

    // ---- P2: per-bucket CSR fill + off/dinv ----
    {
        __syncthreads();                   // LDS region handoff
        if (t < 256) {                     // bbs = excl scan of bucket totals
            int v = (t < nbk) ? cur2[t] : 0;
            int incl = v;
#pragma unroll
            for (int ofs = 1; ofs < 64; ofs <<= 1) {
                int u = __shfl_up(incl, ofs);
                if (lane >= ofs) incl += u;
            }
            if (lane == 63) sm.c.wtot[w] = incl;
            sm.c.bbs[t] = incl - v;
        }
        __syncthreads();
        if (t == 0) {
            int run = 0;
#pragma unroll
            for (int j = 0; j < 4; j++) { sm.c.wpre[j] = run; run += sm.c.wtot[j]; }
        }
        __syncthreads();
        if (t < 256) sm.c.bbs[t] += sm.c.wpre[w];
        __syncthreads();

        for (int b = blockIdx.x; b < nbk; b += gridDim.x) {
            const int node0 = b << BSHIFT;
            const int nlocal = min(BSIZE, N - node0);
            const int pstart = b * BCAP;
            const int pend = pstart + cur2[b];
            const int base_s = sm.c.bbs[b];

            __syncthreads();               // h/cur reuse guard
            if (t < BSIZE) sm.c.h[t] = 0;
            __syncthreads();

            for (int e = pstart + t; e < pend; e += NTHR)
                atomicAdd(&sm.c.h[(int)(pairs[e] >> 32)], 1);
            __syncthreads();

            int deg = 0, incl = 0;
            if (t < BSIZE) {               // waves 0..7
                deg = sm.c.h[t];
                incl = deg;
#pragma unroll
                for (int ofs = 1; ofs < 64; ofs <<= 1) {
                    int u = __shfl_up(incl, ofs);
                    if (lane >= ofs) incl += u;
                }
                if (lane == 63) sm.c.wtot[w] = incl;
            }
            __syncthreads();
            if (t == 0) {
                int run = 0;
#pragma unroll
                for (int j = 0; j < 8; j++) { sm.c.wpre[j] = run; run += sm.c.wtot[j]; }
            }
            __syncthreads();
            if (t < nlocal) {
                int pos = base_s + sm.c.wpre[w] + incl - deg;
                off[node0 + t] = pos;
                sm.c.cur[t] = pos;
                dinv[node0 + t] = rsqrtf((float)(deg + 1));
            }
            __syncthreads();

            for (int e = pstart + t; e < pend; e += NTHR) {
                unsigned long long p = pairs[e];
                int local = (int)(p >> 32);
                int src = (int)(p & 0xffffffffu);
                int pos = atomicAdd(&sm.c.cur[local], 1);
                csr[pos] = src;
            }
        }
    }
    grid.sync();

    gemm_phase(sm, x, 0, W1, dinv, 1, nullptr, Abuf, 1, N);
    grid.sync();
    agg_phase(Abuf, H, off, csr, dinv, b1, N);
    grid.sync();
    gemm_phase(sm, H, 1, W2, dinv, 1, nullptr, Abuf, 1, N);
    grid.sync();
    agg_phase(Abuf, H, off, csr, dinv, b2, N);
    grid.sync();
    gemm_phase(sm, H, 1, W3, dinv, 0, b3, out, 0, N);
}

// ========================= fallback (R7 pipeline) ==========================

__global__ __launch_bounds__(WG) void partition(const int* __restrict__ ei,
                                                int* __restrict__ cur2,
                                                unsigned long long* __restrict__ pairs,
                                                int E) {
    __shared__ int hist[256];
    __shared__ int gbase[256];
    __shared__ int lb[256];
    __shared__ int wtot[4], wpre[4];
    __shared__ unsigned long long sp[PCHUNK];
    __shared__ int sd[PCHUNK];
    const int t = threadIdx.x;
    const int lane = t & 63, w = t >> 6;
    const int base = blockIdx.x * PCHUNK;
    const int total = min(PCHUNK, E - base);

    hist[t] = 0;
    __syncthreads();

    int s[8], d[8], r[8];
#pragma unroll
    for (int i = 0; i < 8; i++) {
        int e = base + i * WG + t;
        bool ok = e < E;
        s[i] = ok ? ei[e] : 0;
        d[i] = ok ? ei[E + e] : 0;
        r[i] = ok ? atomicAdd(&hist[d[i] >> BSHIFT], 1) : 0;
        if (!ok) d[i] = -1;
    }
    __syncthreads();

    int hv = hist[t];
    int old = (hv > 0) ? atomicAdd(&cur2[t], hv) : 0;
    gbase[t] = t * BCAP + old;

    int incl = hv;
#pragma unroll
    for (int ofs = 1; ofs < 64; ofs <<= 1) {
        int u = __shfl_up(incl, ofs);
        if (lane >= ofs) incl += u;
    }
    if (lane == 63) wtot[w] = incl;
    lb[t] = incl - hv;
    __syncthreads();
    if (t == 0) {
        int run = 0;
#pragma unroll
        for (int j = 0; j < 4; j++) { wpre[j] = run; run += wtot[j]; }
    }
    __syncthreads();

#pragma unroll
    for (int i = 0; i < 8; i++) {
        if (d[i] >= 0) {
            int b = d[i] >> BSHIFT;
            int slot = wpre[b >> 6] + lb[b] + r[i];
            sp[slot] = ((unsigned long long)(unsigned)(d[i] & (BSIZE - 1)) << 32) |
                       (unsigned)s[i];
            sd[slot] = gbase[b] + r[i];
        }
    }
    __syncthreads();

    for (int j = t; j < total; j += WG)
        pairs[sd[j]] = sp[j];
}

__global__ __launch_bounds__(1024) void csr_local(const unsigned long long* __restrict__ pairs,
                                                  const int* __restrict__ cur2,
                                                  int* __restrict__ off,
                                                  float* __restrict__ dinv,
                                                  int* __restrict__ csr,
                                                  int N, int nbk, int E) {
    __shared__ int h[BSIZE];
    __shared__ int cur[BSIZE];
    __shared__ int wtot[8], wpre[8];
    __shared__ int base_s;
    const int b = blockIdx.x;
    const int t = threadIdx.x;
    const int node0 = b << BSHIFT;
    const int nlocal = min(BSIZE, N - node0);
    const int pstart = b * BCAP;
    const int pend = pstart + cur2[b];

    if (t < BSIZE) h[t] = 0;
    if (t == 0) {
        int run = 0;
        for (int j = 0; j < b; j++) run += cur2[j];
        base_s = run;
        if (b == 0) off[N] = E;
    }
    __syncthreads();

    for (int e = pstart + t; e < pend; e += 1024)
        atomicAdd(&h[(int)(pairs[e] >> 32)], 1);
    __syncthreads();

    int deg = 0, incl = 0;
    const int lane = t & 63, w = t >> 6;
    if (t < BSIZE) {
        deg = h[t];
        incl = deg;
#pragma unroll
        for (int ofs = 1; ofs < 64; ofs <<= 1) {
            int u = __shfl_up(incl, ofs);
            if (lane >= ofs) incl += u;
        }
        if (lane == 63) wtot[w] = incl;
    }
    __syncthreads();
    if (t == 0) {
        int run = 0;
#pragma unroll
        for (int j = 0; j < 8; j++) { wpre[j] = run; run += wtot[j]; }
    }
    __syncthreads();
    if (t < nlocal) {
        int pos = base_s + wpre[w] + incl - deg;
        off[node0 + t] = pos;
        cur[t] = pos;
        dinv[node0 + t] = rsqrtf((float)(deg + 1));
    }
    __syncthreads();

    for (int e = pstart + t; e < pend; e += 1024) {
        unsigned long long p = pairs[e];
        int local = (int)(p >> 32);
        int src = (int)(p & 0xffffffffu);
        int pos = atomicAdd(&cur[local], 1);
        csr[pos] = src;
    }
}

__global__ __launch_bounds__(WG) void gemm_fused(
    const void* __restrict__ in, int in_bf16, const float* __restrict__ W,
    const float* __restrict__ dinv, int post_scale, const float* __restrict__ b_post,
    void* __restrict__ out1, int out_bf16, int n_rows)
{
    __shared__ float Ws[64 * 64];
    __shared__ float xs[64 * XS_LD];

    const int t = threadIdx.x;
    const int row0 = blockIdx.x * 64;

    const float4* W4 = (const float4*)W;
    float4* Ws4 = (float4*)Ws;
#pragma unroll
    for (int i = 0; i < 4; i++) Ws4[i * WG + t] = W4[i * WG + t];

#pragma unroll
    for (int i = 0; i < 4; i++) {
        int j = i * WG + t;
        int rr = j >> 4;
        int c  = (j & 15) * 4;
        int row = row0 + rr;
        float4 v = make_float4(0.f, 0.f, 0.f, 0.f);
        if (row < n_rows) {
            if (in_bf16) {
                ushort4 u = *(const ushort4*)((const unsigned short*)in +
                                              ((size_t)row << 6) + c);
                union { unsigned q; float f; } a0, a1, a2, a3;
                a0.q = (unsigned)u.x << 16; a1.q = (unsigned)u.y << 16;
                a2.q = (unsigned)u.z << 16; a3.q = (unsigned)u.w << 16;
                v = make_float4(a0.f, a1.f, a2.f, a3.f);
            } else {
                v = *(const float4*)((const float*)in + ((size_t)row << 6) + c);
            }
        }
        float* xp = xs + rr * XS_LD + c;
        xp[0] = v.x; xp[1] = v.y; xp[2] = v.z; xp[3] = v.w;
    }
    __syncthreads();

    const int fg = (t & 15) * 4;
    const int r0 = (t >> 4) * 4;
    float acc[4][4] = {};

#pragma unroll
    for (int kq = 0; kq < 64; kq += 4) {
        float4 xr[4];
#pragma unroll
        for (int r = 0; r < 4; r++)
            xr[r] = *(const float4*)(xs + (r0 + r) * XS_LD + kq);
#pragma unroll
        for (int kk = 0; kk < 4; kk++) {
            float4 wv = *(const float4*)(Ws + (kq + kk) * 64 + fg);
#pragma unroll
            for (int r = 0; r < 4; r++) {
                float xv = ((const float*)&xr[r])[kk];
                acc[r][0] = fmaf(xv, wv.x, acc[r][0]);
                acc[r][1] = fmaf(xv, wv.y, acc[r][1]);
                acc[r][2] = fmaf(xv, wv.z, acc[r][2]);
                acc[r][3] = fmaf(xv, wv.w, acc[r][3]);
            }
        }
    }

    float4 bp = b_post ? *(const float4*)(b_post + fg) : make_float4(0.f, 0.f, 0.f, 0.f);
#pragma unroll
    for (int r = 0; r < 4; r++) {
        int row = row0 + r0 + r;
        if (row >= n_rows) break;
        float sc = post_scale ? dinv[row] : 1.0f;
        float4 o;
        o.x = fmaf(acc[r][0], sc, bp.x);
        o.y = fmaf(acc[r][1], sc, bp.y);
        o.z = fmaf(acc[r][2], sc, bp.z);
        o.w = fmaf(acc[r][3], sc, bp.w);
        if (out_bf16) {
            union { __hip_bfloat16 h[4]; ushort4 u; } pk;
            pk.h[0] = __float2bfloat16(o.x);
            pk.h[1] = __float2bfloat16(o.y);
            pk.h[2] = __float2bfloat16(o.z);
            pk.h[3] = __float2bfloat16(o.w);
            *(ushort4*)((unsigned short*)out1 + ((size_t)row << 6) + fg) = pk.u;
        } else {
            *(float4*)((float*)out1 + ((size_t)row << 6) + fg) = o;
        }
    }
}

__global__ __launch_bounds__(WG) void aggregate(
    const __hip_bfloat16* __restrict__ A, __hip_bfloat16* __restrict__ O,
    const int* __restrict__ off, const int* __restrict__ csr,
    const float* __restrict__ dinv, const float* __restrict__ bias, int N)
{
    int node = blockIdx.x * 4 + (threadIdx.x >> 6);
    if (node >= N) return;
    int lane = threadIdx.x & 63;

    int s0 = off[node];
    int s1 = off[node + 1];
    float acc = __bfloat162float(A[((size_t)node << 6) + lane]);

    int e = s0;
    for (; e + 4 <= s1; e += 4) {
        int i0 = csr[e], i1 = csr[e + 1], i2 = csr[e + 2], i3 = csr[e + 3];
        float v0 = __bfloat162float(A[((size_t)i0 << 6) + lane]);
        float v1 = __bfloat162float(A[((size_t)i1 << 6) + lane]);
        float v2 = __bfloat162float(A[((size_t)i2 << 6) + lane]);
        float v3 = __bfloat162float(A[((size_t)i3 << 6) + lane]);
        acc += (v0 + v1) + (v2 + v3);
    }
    for (; e < s1; e++)
        acc += __bfloat162float(A[((size_t)csr[e] << 6) + lane]);

    float v = fmaxf(fmaf(dinv[node], acc, bias[lane]), 0.f);
    O[((size_t)node << 6) + lane] = __float2bfloat16(v);
}

// ================================ launch ===================================

extern "C" void kernel_launch(void* const* d_in, const int* in_sizes, int n_in,
                              void* d_out, int out_size, void* d_ws, size_t ws_size,
                              hipStream_t stream) {
    const float* x  = (const float*)d_in[0];
    const int*   ei = (const int*)d_in[1];
    const float* W1 = (const float*)d_in[2];
    const float* b1 = (const float*)d_in[3];
    const float* W2 = (const float*)d_in[4];
    const float* b2 = (const float*)d_in[5];
    const float* W3 = (const float*)d_in[6];
    const float* b3 = (const float*)d_in[7];
    float* out = (float*)d_out;

    int N = in_sizes[0] / 64;      // 100000
    int E = in_sizes[1] / 2;       // 1250000
    int nbk = (N + BSIZE - 1) / BSIZE;              // 196

    // workspace layout
    int*   off  = (int*)d_ws;                       // N+1
    int*   csr  = off + (N + 1);                    // E
    int*   cur2 = csr + E;                          // 256 (bucket counts)
    uintptr_t pa = (uintptr_t)(cur2 + 256);
    pa = (pa + 255) & ~(uintptr_t)255;
    float* dinv = (float*)pa;                       // N
    uintptr_t sa = (uintptr_t)(dinv + N);
    sa = (sa + 255) & ~(uintptr_t)255;
    // slab0: pairs (nbk*BCAP*8 = 12.85MB), reused as A (12.8MB bf16) after P2
    unsigned long long* pairs = (unsigned long long*)sa;
    __hip_bfloat16* A = (__hip_bfloat16*)sa;
    size_t slab0 = (size_t)nbk * BCAP * 8;
    __hip_bfloat16* H = (__hip_bfloat16*)(sa + ((slab0 + 255) & ~(size_t)255));

    void* args[] = {
        (void*)&x, (void*)&ei, (void*)&W1, (void*)&b1, (void*)&W2, (void*)&b2,
        (void*)&W3, (void*)&b3, (void*)&out, (void*)&off, (void*)&csr,
        (void*)&cur2, (void*)&dinv, (void*)&pairs, (void*)&A, (void*)&H,
        (void*)&N, (void*)&E, (void*)&nbk
    };
    hipError_t err = hipLaunchCooperativeKernel((const void*)mega, dim3(NBLK),
                                                dim3(NTHR), args, 0, stream);
    if (err != hipSuccess) {
        // R7 multi-kernel fallback (proven 360us path)
        (void)hipGetLastError();           // clear sticky error
        const int gG = (N + 63) / 64;
        const int gA = (N + 3) / 4;
        const int gP = (E + PCHUNK - 1) / PCHUNK;
        hipMemsetAsync(cur2, 0, 256 * sizeof(int), stream);
        partition<<<gP,  WG,   0, stream>>>(ei, cur2, pairs, E);
        csr_local<<<nbk, 1024, 0, stream>>>(pairs, cur2, off, dinv, csr, N, nbk, E);
        gemm_fused<<<gG, WG, 0, stream>>>(x, 0, W1, dinv, 1, nullptr, A, 1, N);
        aggregate <<<gA, WG, 0, stream>>>(A, H, off, csr, dinv, b1, N);
        gemm_fused<<<gG, WG, 0, stream>>>(H, 1, W2, dinv, 1, nullptr, A, 1, N);
        aggregate <<<gA, WG, 0, stream>>>(A, H, off, csr, dinv, b2, N);
        gemm_fused<<<gG, WG, 0, stream>>>(H, 1, W3, dinv, 0, b3, out, 0, N);
    }
}

// Round 10
// 358.392 us; speedup vs baseline: 3.9800x; 3.9800x over previous
//
#include <hip/hip_runtime.h>
#include <hip/hip_bf16.h>

// GCN encoder: 3 layers, N=100000 nodes, E=1250000 edges, 64 features.
// gcn(x) = relu(D^-1/2 (A+I) D^-1/2 (xW) + b)
// A1 = bf16(dinv.*(x@W1)) [gemm1]
// agg_mm(A1,W2): h1_d = relu(dinv_d*(A1_d+sum A1_s)+b1); A2_d = bf16(dinv_d*(h1_d@W2))
// agg_mm(A2,W3): h2_d = relu(dinv_d*(A2_d+sum A2_s)+b2); out_d = h2_d@W3 + b3
// R9 post-mortem: cooperative mega = 4x SLOWER (grid.sync forces cross-XCD L2
//   flush: FETCH 70MB->1.79GB). Reverted to multi-kernel. R10: fuse gemm2/3
//   into the aggregate epilogue (wave holds h in lanes; W in LDS; readlane
//   broadcast; 4 nodes/wave amortizes W reads) -> 6 dispatches, no H buffer.

#define WG 256
#define BSHIFT 9                 // 512 nodes per bucket
#define BSIZE  (1 << BSHIFT)
#define BCAP   8192              // slots per bucket (mean 6400, ~22 sigma margin)
#define PCHUNK 2048              // edges per partition block
#define XS_LD  68                // gemm xs leading dim: 16B-aligned, b128 reads

// Partition edges by dst-bucket into packed pairs ((dst&511)<<32 | src) in
// fixed per-bucket slabs. cur2 = pure counts (memset 0 before). LDS histogram
// -> 1 global atomic per touched bucket -> LDS-staged bucket-ordered output.
__global__ __launch_bounds__(WG) void partition(const int* __restrict__ ei,
                                                int* __restrict__ cur2,
                                                unsigned long long* __restrict__ pairs,
                                                int E) {
    __shared__ int hist[256];
    __shared__ int gbase[256];
    __shared__ int lb[256];
    __shared__ int wtot[4], wpre[4];
    __shared__ unsigned long long sp[PCHUNK];
    __shared__ int sd[PCHUNK];
    const int t = threadIdx.x;
    const int lane = t & 63, w = t >> 6;
    const int base = blockIdx.x * PCHUNK;
    const int total = min(PCHUNK, E - base);

    hist[t] = 0;
    __syncthreads();

    int s[8], d[8], r[8];
#pragma unroll
    for (int i = 0; i < 8; i++) {
        int e = base + i * WG + t;
        bool ok = e < E;
        s[i] = ok ? ei[e] : 0;
        d[i] = ok ? ei[E + e] : 0;
        r[i] = ok ? atomicAdd(&hist[d[i] >> BSHIFT], 1) : 0;
        if (!ok) d[i] = -1;
    }
    __syncthreads();

    int hv = hist[t];
    int old = (hv > 0) ? atomicAdd(&cur2[t], hv) : 0;
    gbase[t] = t * BCAP + old;

    int incl = hv;
#pragma unroll
    for (int ofs = 1; ofs < 64; ofs <<= 1) {
        int u = __shfl_up(incl, ofs);
        if (lane >= ofs) incl += u;
    }
    if (lane == 63) wtot[w] = incl;
    lb[t] = incl - hv;
    __syncthreads();
    if (t == 0) {
        int run = 0;
#pragma unroll
        for (int j = 0; j < 4; j++) { wpre[j] = run; run += wtot[j]; }
    }
    __syncthreads();

#pragma unroll
    for (int i = 0; i < 8; i++) {
        if (d[i] >= 0) {
            int b = d[i] >> BSHIFT;
            int slot = wpre[b >> 6] + lb[b] + r[i];
            sp[slot] = ((unsigned long long)(unsigned)(d[i] & (BSIZE - 1)) << 32) |
                       (unsigned)s[i];
            sd[slot] = gbase[b] + r[i];
        }
    }
    __syncthreads();

    for (int j = t; j < total; j += WG)
        pairs[sd[j]] = sp[j];
}

// Per-bucket CSR fill + off/dinv. Bucket base via in-block shfl scan of cur2
// (R7's serial 196-read prefix removed).
__global__ __launch_bounds__(1024) void csr_local(const unsigned long long* __restrict__ pairs,
                                                  const int* __restrict__ cur2,
                                                  int* __restrict__ off,
                                                  float* __restrict__ dinv,
                                                  int* __restrict__ csr,
                                                  int N, int nbk, int E) {
    __shared__ int h[BSIZE];
    __shared__ int cur[BSIZE];
    __shared__ int wtot[16], wpre[16];
    __shared__ int bbs[256];
    const int b = blockIdx.x;
    const int t = threadIdx.x;
    const int lane = t & 63, w = t >> 6;
    const int node0 = b << BSHIFT;
    const int nlocal = min(BSIZE, N - node0);
    const int pstart = b * BCAP;
    const int pend = pstart + cur2[b];

    // bucket-base = exclusive scan of cur2[0..nbk)
    if (t < 256) {
        int v = (t < nbk) ? cur2[t] : 0;
        int incl = v;
#pragma unroll
        for (int ofs = 1; ofs < 64; ofs <<= 1) {
            int u = __shfl_up(incl, ofs);
            if (lane >= ofs) incl += u;
        }
        if (lane == 63) wtot[w] = incl;
        bbs[t] = incl - v;
    }
    __syncthreads();
    if (t == 0) {
        int run = 0;
#pragma unroll
        for (int j = 0; j < 4; j++) { wpre[j] = run; run += wtot[j]; }
        if (b == 0) off[N] = E;
    }
    __syncthreads();
    const int base_s = bbs[b] + wpre[b >> 6];

    if (t < BSIZE) h[t] = 0;
    __syncthreads();

    for (int e = pstart + t; e < pend; e += 1024)
        atomicAdd(&h[(int)(pairs[e] >> 32)], 1);
    __syncthreads();

    int deg = 0, incl = 0;
    if (t < BSIZE) {
        deg = h[t];
        incl = deg;
#pragma unroll
        for (int ofs = 1; ofs < 64; ofs <<= 1) {
            int u = __shfl_up(incl, ofs);
            if (lane >= ofs) incl += u;
        }
        if (lane == 63) wtot[w] = incl;
    }
    __syncthreads();
    if (t == 0) {
        int run = 0;
#pragma unroll
        for (int j = 0; j < 8; j++) { wpre[j] = run; run += wtot[j]; }
    }
    __syncthreads();
    if (t < nlocal) {
        int pos = base_s + wpre[w] + incl - deg;
        off[node0 + t] = pos;
        cur[t] = pos;
        dinv[node0 + t] = rsqrtf((float)(deg + 1));
    }
    __syncthreads();

    for (int e = pstart + t; e < pend; e += 1024) {
        unsigned long long p = pairs[e];
        int local = (int)(p >> 32);
        int src = (int)(p & 0xffffffffu);
        int pos = atomicAdd(&cur[local], 1);
        csr[pos] = src;
    }
}

// gemm1: A1 = bf16(dinv[row] * (x @ W1)).  64-row tile, 4x4 reg tile/thread.
__global__ __launch_bounds__(WG) void gemm_fused(
    const float* __restrict__ in, const float* __restrict__ W,
    const float* __restrict__ dinv, __hip_bfloat16* __restrict__ out1, int n_rows)
{
    __shared__ float Ws[64 * 64];
    __shared__ float xs[64 * XS_LD];

    const int t = threadIdx.x;
    const int row0 = blockIdx.x * 64;

    const float4* W4 = (const float4*)W;
    float4* Ws4 = (float4*)Ws;
#pragma unroll
    for (int i = 0; i < 4; i++) Ws4[i * WG + t] = W4[i * WG + t];

#pragma unroll
    for (int i = 0; i < 4; i++) {
        int j = i * WG + t;
        int rr = j >> 4;
        int c  = (j & 15) * 4;
        int row = row0 + rr;
        float4 v = make_float4(0.f, 0.f, 0.f, 0.f);
        if (row < n_rows)
            v = *(const float4*)(in + ((size_t)row << 6) + c);
        float* xp = xs + rr * XS_LD + c;
        xp[0] = v.x; xp[1] = v.y; xp[2] = v.z; xp[3] = v.w;
    }
    __syncthreads();

    const int fg = (t & 15) * 4;
    const int r0 = (t >> 4) * 4;
    float acc[4][4] = {};

#pragma unroll
    for (int kq = 0; kq < 64; kq += 4) {
        float4 xr[4];
#pragma unroll
        for (int r = 0; r < 4; r++)
            xr[r] = *(const float4*)(xs + (r0 + r) * XS_LD + kq);
#pragma unroll
        for (int kk = 0; kk < 4; kk++) {
            float4 wv = *(const float4*)(Ws + (kq + kk) * 64 + fg);
#pragma unroll
            for (int r = 0; r < 4; r++) {
                float xv = ((const float*)&xr[r])[kk];
                acc[r][0] = fmaf(xv, wv.x, acc[r][0]);
                acc[r][1] = fmaf(xv, wv.y, acc[r][1]);
                acc[r][2] = fmaf(xv, wv.z, acc[r][2]);
                acc[r][3] = fmaf(xv, wv.w, acc[r][3]);
            }
        }
    }

#pragma unroll
    for (int r = 0; r < 4; r++) {
        int row = row0 + r0 + r;
        if (row >= n_rows) break;
        float sc = dinv[row];
        union { __hip_bfloat16 h[4]; ushort4 u; } pk;
        pk.h[0] = __float2bfloat16(acc[r][0] * sc);
        pk.h[1] = __float2bfloat16(acc[r][1] * sc);
        pk.h[2] = __float2bfloat16(acc[r][2] * sc);
        pk.h[3] = __float2bfloat16(acc[r][3] * sc);
        *(ushort4*)((unsigned short*)out1 + ((size_t)row << 6) + fg) = pk.u;
    }
}

__device__ __forceinline__ float rdlane(float v, int k) {
    return __uint_as_float(__builtin_amdgcn_readlane(__float_as_uint(v), k));
}

// Fused aggregate + next-layer GEMM.  One wave handles 4 nodes:
//   h_i = relu(dinv*(A[n_i] + sum A[csr]) + b_in)   (gather, lane = feature)
//   o_i = h_i @ Wn   (Wn in LDS; per k: 1 broadcast row read + 4 readlane-FMA)
// out: bf16(dinv*o) (next gather array) or fp32 o + b_out (final output).
// Grid: each block stages Wn once, processes 2 passes x 16 nodes.
__global__ __launch_bounds__(WG) void agg_mm(
    const __hip_bfloat16* __restrict__ A,
    const int* __restrict__ off, const int* __restrict__ csr,
    const float* __restrict__ dinv, const float* __restrict__ b_in,
    const float* __restrict__ Wn, const float* __restrict__ b_out,
    void* __restrict__ outp, int out_bf16, int N)
{
    __shared__ float Ws[64 * 64];
    const int t = threadIdx.x;
    {
        const float4* W4 = (const float4*)Wn;
        float4* S4 = (float4*)Ws;
#pragma unroll
        for (int i = 0; i < 4; i++) S4[i * WG + t] = W4[i * WG + t];
    }
    __syncthreads();

    const int lane = t & 63;
    const int wv = t >> 6;
    const float bin = b_in[lane];
    const float bout = b_out ? b_out[lane] : 0.f;

#pragma unroll
    for (int p = 0; p < 2; p++) {
        const int nb = (blockIdx.x * 2 + p) * 16 + wv * 4;   // first of 4 nodes
        if (nb >= N) break;

        float h[4];
#pragma unroll
        for (int i = 0; i < 4; i++) {
            int node = nb + i;
            if (node < N) {
                int s0 = off[node], s1 = off[node + 1];
                float acc = __bfloat162float(A[((size_t)node << 6) + lane]); // self
                int e = s0;
                for (; e + 4 <= s1; e += 4) {
                    int i0 = csr[e], i1 = csr[e+1], i2 = csr[e+2], i3 = csr[e+3];
                    float v0 = __bfloat162float(A[((size_t)i0 << 6) + lane]);
                    float v1 = __bfloat162float(A[((size_t)i1 << 6) + lane]);
                    float v2 = __bfloat162float(A[((size_t)i2 << 6) + lane]);
                    float v3 = __bfloat162float(A[((size_t)i3 << 6) + lane]);
                    acc += (v0 + v1) + (v2 + v3);
                }
                for (; e < s1; e++)
                    acc += __bfloat162float(A[((size_t)csr[e] << 6) + lane]);
                h[i] = fmaxf(fmaf(dinv[node], acc, bin), 0.f);
            } else {
                h[i] = 0.f;
            }
        }

        float o0 = 0.f, o1 = 0.f, o2 = 0.f, o3 = 0.f;
#pragma unroll
        for (int k = 0; k < 64; k++) {
            float wk = Ws[(k << 6) + lane];          // row broadcast, conflict-free
            o0 = fmaf(rdlane(h[0], k), wk, o0);
            o1 = fmaf(rdlane(h[1], k), wk, o1);
            o2 = fmaf(rdlane(h[2], k), wk, o2);
            o3 = fmaf(rdlane(h[3], k), wk, o3);
        }

        float os[4] = {o0, o1, o2, o3};
#pragma unroll
        for (int i = 0; i < 4; i++) {
            int node = nb + i;
            if (node >= N) break;
            if (out_bf16) {
                ((__hip_bfloat16*)outp)[((size_t)node << 6) + lane] =
                    __float2bfloat16(dinv[node] * os[i]);
            } else {
                ((float*)outp)[((size_t)node << 6) + lane] = os[i] + bout;
            }
        }
    }
}

extern "C" void kernel_launch(void* const* d_in, const int* in_sizes, int n_in,
                              void* d_out, int out_size, void* d_ws, size_t ws_size,
                              hipStream_t stream) {
    const float* x  = (const float*)d_in[0];
    const int*   ei = (const int*)d_in[1];
    const float* W1 = (const float*)d_in[2];
    const float* b1 = (const float*)d_in[3];
    const float* W2 = (const float*)d_in[4];
    const float* b2 = (const float*)d_in[5];
    const float* W3 = (const float*)d_in[6];
    const float* b3 = (const float*)d_in[7];
    float* out = (float*)d_out;

    const int N = in_sizes[0] / 64;    // 100000
    const int E = in_sizes[1] / 2;     // 1250000
    const int nbk = (N + BSIZE - 1) / BSIZE;        // 196

    // workspace layout
    int*   off  = (int*)d_ws;                       // N+1
    int*   csr  = off + (N + 1);                    // E
    int*   cur2 = csr + E;                          // 256 (bucket counts)
    uintptr_t pa = (uintptr_t)(cur2 + 256);
    pa = (pa + 255) & ~(uintptr_t)255;
    float* dinv = (float*)pa;                       // N
    uintptr_t sa = (uintptr_t)(dinv + N);
    sa = (sa + 255) & ~(uintptr_t)255;
    // slab0: pairs (nbk*BCAP*8 = 12.85MB), reused as A1 (12.8MB bf16) after build
    unsigned long long* pairs = (unsigned long long*)sa;
    __hip_bfloat16* A1 = (__hip_bfloat16*)sa;
    size_t slab0 = (size_t)nbk * BCAP * 8;
    __hip_bfloat16* A2 = (__hip_bfloat16*)(sa + ((slab0 + 255) & ~(size_t)255));

    const int gG = (N + 63) / 64;                   // 1563
    const int gP = (E + PCHUNK - 1) / PCHUNK;       // 611
    const int gA = (N + 31) / 32;                   // 3125 (2 passes x 16 nodes)

    hipMemsetAsync(cur2, 0, 256 * sizeof(int), stream);
    partition<<<gP,  WG,   0, stream>>>(ei, cur2, pairs, E);
    csr_local<<<nbk, 1024, 0, stream>>>(pairs, cur2, off, dinv, csr, N, nbk, E);

    // Layer 1 GEMM: A1 = bf16(dinv .* (x @ W1))
    gemm_fused<<<gG, WG, 0, stream>>>(x, W1, dinv, A1, N);
    // Layer 1 agg + Layer 2 GEMM: A2 = bf16(dinv .* (relu(dinv*(agg A1)+b1) @ W2))
    agg_mm<<<gA, WG, 0, stream>>>(A1, off, csr, dinv, b1, W2, nullptr, A2, 1, N);
    // Layer 2 agg + Layer 3 GEMM: out = relu(dinv*(agg A2)+b2) @ W3 + b3
    agg_mm<<<gA, WG, 0, stream>>>(A2, off, csr, dinv, b2, W3, b3, out, 0, N);
}